// Round 1
// baseline (454.552 us; speedup 1.0000x reference)
//
#include <hip/hip_runtime.h>

#define N_NODES 100000
#define D_FEAT  128
#define N_EDGES 625000

// Kernel 1: out = ds_out (float4-vectorized copy; out is poisoned 0xAA each call)
__global__ void init_out_kernel(const float4* __restrict__ ds_out,
                                float4* __restrict__ out, int n4) {
    int i = blockIdx.x * blockDim.x + threadIdx.x;
    if (i < n4) out[i] = ds_out[i];
}

// Kernel 2: per edge, atomically add ds_in[src] row into out[recv] row, count degree.
// 128 threads per edge (2 edges per 256-thread block). Loads of ds_in[src*128+f]
// are coalesced (512 contiguous bytes per edge-half-block).
__global__ void scatter_kernel(const float* __restrict__ ds_in,
                               const int* __restrict__ recv_idx,
                               const int* __restrict__ src_idx,
                               float* __restrict__ out,
                               int* __restrict__ deg) {
    int e = blockIdx.x * 2 + (threadIdx.x >> 7);
    int f = threadIdx.x & 127;
    if (e >= N_EDGES) return;
    int r = recv_idx[e];
    int s = src_idx[e];
    if (f == 0) atomicAdd(&deg[r], 1);
    // hardware global_atomic_add_f32 (denorm-flush OK for this data)
    unsafeAtomicAdd(&out[r * D_FEAT + f], ds_in[s * D_FEAT + f]);
}

// Kernel 3: out[row] *= 1/(deg[row]+1), float4-vectorized.
__global__ void finalize_kernel(const int* __restrict__ deg,
                                float4* __restrict__ out, int n4) {
    int i = blockIdx.x * blockDim.x + threadIdx.x;
    if (i >= n4) return;
    int row = i >> 5;  // 32 float4 per row (128 floats)
    float inv = 1.0f / (float)(deg[row] + 1);
    float4 v = out[i];
    v.x *= inv; v.y *= inv; v.z *= inv; v.w *= inv;
    out[i] = v;
}

extern "C" void kernel_launch(void* const* d_in, const int* in_sizes, int n_in,
                              void* d_out, int out_size, void* d_ws, size_t ws_size,
                              hipStream_t stream) {
    const float* ds_in  = (const float*)d_in[0];
    const float* ds_out = (const float*)d_in[1];
    const int*   eidx   = (const int*)d_in[2];   // [2, N_EDGES] row-major, int32
    float* out = (float*)d_out;
    int*   deg = (int*)d_ws;                      // N_NODES ints of scratch

    // zero the degree accumulator (d_ws is re-poisoned 0xAA before every call)
    hipMemsetAsync(deg, 0, N_NODES * sizeof(int), stream);

    const int n4 = N_NODES * D_FEAT / 4;          // 3.2M float4
    init_out_kernel<<<(n4 + 255) / 256, 256, 0, stream>>>(
        (const float4*)ds_out, (float4*)out, n4);

    const int n_edge_blocks = (N_EDGES + 1) / 2;  // 2 edges per block
    scatter_kernel<<<n_edge_blocks, 256, 0, stream>>>(
        ds_in, eidx, eidx + N_EDGES, out, deg);

    finalize_kernel<<<(n4 + 255) / 256, 256, 0, stream>>>(deg, (float4*)out, n4);
}

// Round 2
// 250.627 us; speedup vs baseline: 1.8137x; 1.8137x over previous
//
#include <hip/hip_runtime.h>

#define N_NODES 100000
#define D_FEAT  128
#define N_EDGES 625000
#define SCAN_B  1024
#define NB      ((N_NODES + SCAN_B - 1) / SCAN_B)   // 98 scan blocks

// --- CSR build ---------------------------------------------------------------

__global__ void histogram_kernel(const int* __restrict__ recv, int* __restrict__ deg) {
    int e = blockIdx.x * blockDim.x + threadIdx.x;
    if (e < N_EDGES) atomicAdd(&deg[recv[e]], 1);
}

// per-1024-chunk sums of deg
__global__ void block_sums_kernel(const int* __restrict__ deg, int* __restrict__ bsum) {
    __shared__ int s[SCAN_B];
    int b = blockIdx.x, t = threadIdx.x;
    int i = b * SCAN_B + t;
    s[t] = (i < N_NODES) ? deg[i] : 0;
    __syncthreads();
    for (int off = SCAN_B / 2; off > 0; off >>= 1) {
        if (t < off) s[t] += s[t + off];
        __syncthreads();
    }
    if (t == 0) bsum[b] = s[0];
}

// exclusive scan of the 98 block sums (single block, LDS Hillis-Steele)
__global__ void scan_bsums_kernel(int* __restrict__ bsum) {
    __shared__ int tmp[128];
    int t = threadIdx.x;
    int v = (t < NB) ? bsum[t] : 0;
    tmp[t] = v;
    __syncthreads();
    for (int off = 1; off < 128; off <<= 1) {
        int x = (t >= off) ? tmp[t - off] : 0;
        __syncthreads();
        tmp[t] += x;
        __syncthreads();
    }
    if (t < NB) bsum[t] = tmp[t] - v;   // exclusive
}

// per-chunk exclusive scan + chunk base -> offsets; also init cursor
__global__ void scan_blocks_kernel(const int* __restrict__ deg, const int* __restrict__ bsum,
                                   int* __restrict__ offsets, int* __restrict__ cursor) {
    __shared__ int tmp[SCAN_B];
    int b = blockIdx.x, t = threadIdx.x;
    int i = b * SCAN_B + t;
    int v = (i < N_NODES) ? deg[i] : 0;
    tmp[t] = v;
    __syncthreads();
    for (int off = 1; off < SCAN_B; off <<= 1) {
        int x = (t >= off) ? tmp[t - off] : 0;
        __syncthreads();
        tmp[t] += x;
        __syncthreads();
    }
    if (i < N_NODES) {
        int excl = bsum[b] + tmp[t] - v;
        offsets[i] = excl;
        cursor[i]  = excl;
    }
}

__global__ void reorder_kernel(const int* __restrict__ recv, const int* __restrict__ src,
                               int* __restrict__ cursor, int* __restrict__ ssrc) {
    int e = blockIdx.x * blockDim.x + threadIdx.x;
    if (e >= N_EDGES) return;
    int r = recv[e];
    int pos = atomicAdd(&cursor[r], 1);
    ssrc[pos] = src[e];
}

// --- Gather: 32 lanes per node, float4 per lane (128 floats/row) -------------

__global__ void gather_kernel(const float4* __restrict__ ds_in4,
                              const float4* __restrict__ ds_out4,
                              const int* __restrict__ offsets,
                              const int* __restrict__ deg,
                              const int* __restrict__ ssrc,
                              float4* __restrict__ out4) {
    int node = blockIdx.x * 8 + (threadIdx.x >> 5);
    int lane = threadIdx.x & 31;
    if (node >= N_NODES) return;
    int beg = offsets[node];
    int d   = deg[node];
    float4 acc = ds_out4[node * 32 + lane];
    for (int k = 0; k < d; k++) {
        int s = ssrc[beg + k];                 // uniform across the 32-lane group
        float4 v = ds_in4[s * 32 + lane];      // 512 B coalesced row segment
        acc.x += v.x; acc.y += v.y; acc.z += v.z; acc.w += v.w;
    }
    float inv = 1.0f / (1.0f + (float)d);
    acc.x *= inv; acc.y *= inv; acc.z *= inv; acc.w *= inv;
    out4[node * 32 + lane] = acc;
}

// --- launch ------------------------------------------------------------------

extern "C" void kernel_launch(void* const* d_in, const int* in_sizes, int n_in,
                              void* d_out, int out_size, void* d_ws, size_t ws_size,
                              hipStream_t stream) {
    const float* ds_in  = (const float*)d_in[0];
    const float* ds_out = (const float*)d_in[1];
    const int*   eidx   = (const int*)d_in[2];   // [2, N_EDGES] row-major int32
    const int* recv = eidx;
    const int* src  = eidx + N_EDGES;
    float* out = (float*)d_out;

    // workspace layout (ints)
    int* deg     = (int*)d_ws;               // N_NODES
    int* offsets = deg + N_NODES;            // N_NODES
    int* cursor  = offsets + N_NODES;        // N_NODES
    int* bsum    = cursor + N_NODES;         // 128 (NB=98 used)
    int* ssrc    = bsum + 128;               // N_EDGES

    hipMemsetAsync(deg, 0, N_NODES * sizeof(int), stream);

    histogram_kernel<<<(N_EDGES + 255) / 256, 256, 0, stream>>>(recv, deg);
    block_sums_kernel<<<NB, SCAN_B, 0, stream>>>(deg, bsum);
    scan_bsums_kernel<<<1, 128, 0, stream>>>(bsum);
    scan_blocks_kernel<<<NB, SCAN_B, 0, stream>>>(deg, bsum, offsets, cursor);
    reorder_kernel<<<(N_EDGES + 255) / 256, 256, 0, stream>>>(recv, src, cursor, ssrc);

    gather_kernel<<<(N_NODES + 7) / 8, 256, 0, stream>>>(
        (const float4*)ds_in, (const float4*)ds_out, offsets, deg, ssrc, (float4*)out);
}

// Round 3
// 217.308 us; speedup vs baseline: 2.0917x; 1.1533x over previous
//
#include <hip/hip_runtime.h>

#define N_NODES 100000
#define D_FEAT  128
#define N_EDGES 625000

// Build per-node edge linked lists: head[node] -> edge -> next[edge] -> ... -> -1.
// One atomicExch per edge; next[e] written only by thread e (no race).
__global__ void build_links_kernel(const int* __restrict__ recv,
                                   int* __restrict__ head,
                                   int* __restrict__ next) {
    int e = blockIdx.x * blockDim.x + threadIdx.x;
    if (e >= N_EDGES) return;
    int r = recv[e];
    next[e] = atomicExch(&head[r], e);
}

// Gather: 32 lanes per node (float4 per lane = 128 floats/row). Walk the chain,
// accumulate ds_in rows in registers, count degree, scale, single coalesced write.
__global__ void gather_kernel(const float4* __restrict__ ds_in4,
                              const float4* __restrict__ ds_out4,
                              const int* __restrict__ head,
                              const int* __restrict__ next,
                              const int* __restrict__ src,
                              float4* __restrict__ out4) {
    int node = blockIdx.x * 8 + (threadIdx.x >> 5);
    int lane = threadIdx.x & 31;
    if (node >= N_NODES) return;

    float4 acc = ds_out4[node * 32 + lane];
    int d = 0;
    int e = head[node];                      // wave-uniform
    while (e >= 0) {
        int en = next[e];                    // issue chase + src load together,
        int s  = src[e];                     // row load depends only on s
        float4 v = ds_in4[s * 32 + lane];    // 512 B coalesced row segment
        acc.x += v.x; acc.y += v.y; acc.z += v.z; acc.w += v.w;
        d++;
        e = en;
    }
    float inv = 1.0f / (1.0f + (float)d);
    acc.x *= inv; acc.y *= inv; acc.z *= inv; acc.w *= inv;
    out4[node * 32 + lane] = acc;
}

extern "C" void kernel_launch(void* const* d_in, const int* in_sizes, int n_in,
                              void* d_out, int out_size, void* d_ws, size_t ws_size,
                              hipStream_t stream) {
    const float* ds_in  = (const float*)d_in[0];
    const float* ds_out = (const float*)d_in[1];
    const int*   eidx   = (const int*)d_in[2];   // [2, N_EDGES] row-major int32
    const int* recv = eidx;
    const int* src  = eidx + N_EDGES;
    float* out = (float*)d_out;

    int* head = (int*)d_ws;          // N_NODES
    int* next = head + N_NODES;      // N_EDGES

    // head = -1 everywhere (0xFFFFFFFF)
    hipMemsetAsync(head, 0xFF, N_NODES * sizeof(int), stream);

    build_links_kernel<<<(N_EDGES + 255) / 256, 256, 0, stream>>>(recv, head, next);

    gather_kernel<<<(N_NODES + 7) / 8, 256, 0, stream>>>(
        (const float4*)ds_in, (const float4*)ds_out, head, next, src, (float4*)out);
}

// Round 4
// 213.139 us; speedup vs baseline: 2.1327x; 1.0196x over previous
//
#include <hip/hip_runtime.h>

#define N_NODES 100000
#define D_FEAT  128
#define N_EDGES 625000

#define NBUCKET 256
#define NPB     391      // nodes per bucket: 256*391 = 100096 >= 100000
#define NCHUNK  125
#define CHUNK   5000     // 125*5000 = 625000 exactly

typedef float vfloat4 __attribute__((ext_vector_type(4)));

// Pass A: per-chunk histogram over 256 node-buckets (LDS only)
__global__ void count_kernel(const int* __restrict__ recv, int* __restrict__ counts) {
    __shared__ int hist[NBUCKET];
    int c = blockIdx.x;
    for (int i = threadIdx.x; i < NBUCKET; i += 256) hist[i] = 0;
    __syncthreads();
    const int base = c * CHUNK;
    for (int i = threadIdx.x; i < CHUNK; i += 256) {
        int r = recv[base + i];
        atomicAdd(&hist[r / NPB], 1);          // LDS atomic
    }
    __syncthreads();
    for (int b = threadIdx.x; b < NBUCKET; b += 256)
        counts[b * NCHUNK + c] = hist[b];
}

// Pass B: per-bucket exclusive scan over its 125 chunk counts
__global__ void scan_chunks_kernel(int* __restrict__ counts, int* __restrict__ btotal) {
    __shared__ int tmp[128];
    int b = blockIdx.x, t = threadIdx.x;
    int v = (t < NCHUNK) ? counts[b * NCHUNK + t] : 0;
    tmp[t] = v;
    __syncthreads();
    for (int off = 1; off < 128; off <<= 1) {
        int x = (t >= off) ? tmp[t - off] : 0;
        __syncthreads();
        tmp[t] += x;
        __syncthreads();
    }
    if (t < NCHUNK) counts[b * NCHUNK + t] = tmp[t] - v;   // exclusive
    if (t == 127) btotal[b] = tmp[127];                    // bucket total
}

// Pass B2: exclusive scan of 256 bucket totals -> bucket bases
__global__ void scan_buckets_kernel(const int* __restrict__ btotal, int* __restrict__ bbase) {
    __shared__ int tmp[NBUCKET];
    int t = threadIdx.x;
    int v = btotal[t];
    tmp[t] = v;
    __syncthreads();
    for (int off = 1; off < NBUCKET; off <<= 1) {
        int x = (t >= off) ? tmp[t - off] : 0;
        __syncthreads();
        tmp[t] += x;
        __syncthreads();
    }
    bbase[t] = tmp[t] - v;
}

// Pass C: scatter packed (local<<17|src) into bucket-grouped order (LDS cursors only)
__global__ void scatter_kernel(const int* __restrict__ recv, const int* __restrict__ src,
                               const int* __restrict__ counts, const int* __restrict__ bbase,
                               int* __restrict__ packed) {
    __shared__ int cur[NBUCKET];
    int p = blockIdx.x;
    int c = (p & 7) * 16 + (p >> 3);           // consecutive chunks -> same XCD
    if (c >= NCHUNK) return;
    for (int i = threadIdx.x; i < NBUCKET; i += 256)
        cur[i] = bbase[i] + counts[i * NCHUNK + c];
    __syncthreads();
    const int base = c * CHUNK;
    for (int i = threadIdx.x; i < CHUNK; i += 256) {
        int r = recv[base + i];
        int s = src[base + i];
        int b = r / NPB;
        int pos = atomicAdd(&cur[b], 1);       // LDS atomic
        packed[pos] = ((r - b * NPB) << 17) | s;
    }
}

// Pass D: per-bucket in-LDS counting sort -> global CSR (ssrc + {offset,deg} per node)
__global__ __launch_bounds__(512) void binify_kernel(const int* __restrict__ packed,
                                                     const int* __restrict__ bbase,
                                                     const int* __restrict__ btotal,
                                                     int* __restrict__ ssrc,
                                                     int2* __restrict__ nodeinfo) {
    __shared__ int dcnt[512], dsc[512];
    int b = blockIdx.x, t = threadIdx.x;
    int beg = bbase[b], cnt = btotal[b];
    dcnt[t] = 0;
    __syncthreads();
    for (int i = t; i < cnt; i += 512)
        atomicAdd(&dcnt[packed[beg + i] >> 17], 1);
    __syncthreads();
    int v = dcnt[t];
    dsc[t] = v;
    __syncthreads();
    for (int off = 1; off < 512; off <<= 1) {
        int x = (t >= off) ? dsc[t - off] : 0;
        __syncthreads();
        dsc[t] += x;
        __syncthreads();
    }
    int excl = dsc[t] - v;
    int node = b * NPB + t;
    if (t < NPB && node < N_NODES)
        nodeinfo[node] = make_int2(beg + excl, v);
    dcnt[t] = excl;                            // reuse as cursor
    __syncthreads();
    for (int i = t; i < cnt; i += 512) {
        int pk = packed[beg + i];
        int slot = atomicAdd(&dcnt[pk >> 17], 1);   // LDS atomic
        ssrc[beg + slot] = pk & 0x1FFFF;
    }
}

// Pass E: CSR gather, 32 lanes/node, float4/lane; nontemporal on streaming rows
__global__ void gather_kernel(const vfloat4* __restrict__ ds_in4,
                              const vfloat4* __restrict__ ds_out4,
                              const int2* __restrict__ nodeinfo,
                              const int* __restrict__ ssrc,
                              vfloat4* __restrict__ out4) {
    int node = blockIdx.x * 8 + (threadIdx.x >> 5);
    int lane = threadIdx.x & 31;
    if (node >= N_NODES) return;
    int2 info = nodeinfo[node];
    int beg = info.x, d = info.y;
    vfloat4 acc = __builtin_nontemporal_load(&ds_out4[node * 32 + lane]);
    for (int k = 0; k < d; k++) {
        int s = ssrc[beg + k];                 // uniform across the 32-lane group
        vfloat4 vv = ds_in4[s * 32 + lane];    // 512 B coalesced row segment
        acc += vv;
    }
    float inv = 1.0f / (1.0f + (float)d);
    acc *= inv;
    __builtin_nontemporal_store(acc, &out4[node * 32 + lane]);
}

extern "C" void kernel_launch(void* const* d_in, const int* in_sizes, int n_in,
                              void* d_out, int out_size, void* d_ws, size_t ws_size,
                              hipStream_t stream) {
    const float* ds_in  = (const float*)d_in[0];
    const float* ds_out = (const float*)d_in[1];
    const int*   eidx   = (const int*)d_in[2];   // [2, N_EDGES] row-major int32
    const int* recv = eidx;
    const int* src  = eidx + N_EDGES;
    float* out = (float*)d_out;

    // workspace layout (no init required: every cell is written before read)
    int*  counts   = (int*)d_ws;                     // NBUCKET*NCHUNK = 32000
    int*  btotal   = counts + NBUCKET * NCHUNK;      // 256
    int*  bbase    = btotal + NBUCKET;               // 256
    int*  packed   = bbase + NBUCKET;                // N_EDGES
    int*  ssrc     = packed + N_EDGES;               // N_EDGES
    int2* nodeinfo = (int2*)(ssrc + N_EDGES);        // N_NODES int2

    count_kernel<<<NCHUNK, 256, 0, stream>>>(recv, counts);
    scan_chunks_kernel<<<NBUCKET, 128, 0, stream>>>(counts, btotal);
    scan_buckets_kernel<<<1, NBUCKET, 0, stream>>>(btotal, bbase);
    scatter_kernel<<<128, 256, 0, stream>>>(recv, src, counts, bbase, packed);
    binify_kernel<<<NBUCKET, 512, 0, stream>>>(packed, bbase, btotal, ssrc, nodeinfo);
    gather_kernel<<<(N_NODES + 7) / 8, 256, 0, stream>>>(
        (const vfloat4*)ds_in, (const vfloat4*)ds_out, nodeinfo, ssrc, (vfloat4*)out);
}